// Round 15
// baseline (43.119 us; speedup 1.0000x reference)
//
#include <hip/hip_runtime.h>
#include <math.h>

#define NT 512
#define NWAVE 8
#define WPITCH 65           // padded pitch (f32) -- conflict-free strided reads

// Kernel 1: grid 1280 = (theta t5 = bx>>8) x (bt = bx&255), 512 threads.
// 8 waves; lane = channel hh; wave w owns strips {w, w+8} (9 shifts each):
// span(w)+span(w+8) == L exactly -> perfect balance. Window table f32 in LDS
// (pitch 65). Dots/ss in f32 (same bits/order as round-14's passing kernel);
// candidate comparison via exact f64 cross-multiplication of f32-origin
// values (24-bit mantissas -> exact products) -> deterministic ordering,
// first-index ties. LDS ~31 KB, VGPR <= 64 -> 4 blocks/CU (32 waves).
__global__ __launch_bounds__(NT) void argaug_scan(
    const float* __restrict__ x, const float* __restrict__ y,
    const int* __restrict__ mask,
    const float* __restrict__ W1, const float* __restrict__ b1,
    const float* __restrict__ W2, const float* __restrict__ b2,
    double* __restrict__ outN, double* __restrict__ outD, int* __restrict__ outS)
{
    __shared__ float  wdBuf[76 * WPITCH];      // 19760 B
    __shared__ float  ypad[80];                // ypad[p] = y[p-8], p in [8,71], else 0
    __shared__ float  sx[64], sh[64], sb1[64];
    __shared__ double rsimN[NWAVE * 64], rsimD[NWAVE * 64];
    __shared__ int    ridxB[NWAVE * 64];

    const int tid = threadIdx.x;
    const int bx  = blockIdx.x;
    const int bt  = bx & 255;
    const int t5  = bx >> 8;
    const int hh  = tid & 63;
    const int sg  = tid >> 6;

    const double theta = (t5 == 4) ? 1.2 : (0.8 + (double)t5 * ((1.2 - 0.8) / 4.0));
    const int L = (int)floor(64.0 * theta);   // {51,57,64,70,76}
    const int S = L + 63;
    const double rcp = 64.0 / (double)L;

    if (tid < 64) {
        sx[tid]  = x[bt * 64 + tid];
        sb1[tid] = b1[tid];
    } else if (tid >= 128 && tid < 208) {
        const int p = tid - 128;
        ypad[p] = (p >= 8 && p < 72) ? y[bt * 64 + p - 8] : 0.0f;
    }
    __syncthreads();

    if (tid < 64) {
        // fc1: serial fmaf chain, bitwise-identical across all rounds
        float acc = 0.0f;
        const float* w1r = W1 + tid * 64;
        for (int i = 0; i < 64; ++i) acc = fmaf(sx[i], w1r[i], acc);
        acc += sb1[tid];
        sh[tid] = acc * (float)mask[bt * 64 + tid];
    }
    __syncthreads();

    // Phase A: wd[j][h] = sh[h]*W2[src(j)][h] + b2[src(j)]  (f32)
    for (int k = tid; k < L * 64; k += NT) {
        const int j = k >> 6, h = k & 63;     // j wave-uniform
        int sj = (int)floor((double)j * rcp);
        if (sj > 63) sj = 63;
        wdBuf[j * WPITCH + h] = fmaf(sh[h], W2[sj * 64 + h], b2[sj]);
    }
    __syncthreads();

    const float* wrow = wdBuf + hh;           // row j at wrow[j*WPITCH]

    double bN = -1.0, bD = 0.0; int bi = 0x7fffffff;
    #pragma unroll 2
    for (int pp = 0; pp < 2; ++pp) {
        const int s_first = 9 * (sg + 8 * pp);
        if (s_first >= S) continue;
        const int jstart = (s_first > 63) ? (s_first - 63) : 0;
        const int jmid   = (s_first < L - 1) ? s_first : (L - 1);
        const int jend   = (s_first + 8 < L - 1) ? (s_first + 8) : (L - 1);
        const int C      = 71 - s_first;      // ypad idx = j + C - k

        float d0=0,d1=0,d2=0,d3=0,d4=0,d5=0,d6=0,d7=0,d8=0,ssA=0;
        float ym1 = ypad[jstart + C - 1];
        float ym2 = ypad[jstart + C - 2];
        float ym3 = ypad[jstart + C - 3];
        float ym4 = ypad[jstart + C - 4];
        float ym5 = ypad[jstart + C - 5];
        float ym6 = ypad[jstart + C - 6];
        float ym7 = ypad[jstart + C - 7];
        float ym8 = ypad[jstart + C - 8];

        #pragma unroll 9
        for (int j = jstart; j <= jmid; ++j) {
            const float w  = wrow[j * WPITCH];
            const float y0 = ypad[j + C];
            d0 = fmaf(w, y0,  d0); d1 = fmaf(w, ym1, d1); d2 = fmaf(w, ym2, d2);
            d3 = fmaf(w, ym3, d3); d4 = fmaf(w, ym4, d4); d5 = fmaf(w, ym5, d5);
            d6 = fmaf(w, ym6, d6); d7 = fmaf(w, ym7, d7); d8 = fmaf(w, ym8, d8);
            ssA = fmaf(w, w, ssA);
            ym8=ym7; ym7=ym6; ym6=ym5; ym5=ym4; ym4=ym3; ym3=ym2; ym2=ym1; ym1=y0;
        }
        #pragma unroll 9
        for (int j = jmid + 1; j <= jend; ++j) {
            const float w  = wrow[j * WPITCH];
            const float y0 = ypad[j + C];
            d0 = fmaf(w, y0,  d0); d1 = fmaf(w, ym1, d1); d2 = fmaf(w, ym2, d2);
            d3 = fmaf(w, ym3, d3); d4 = fmaf(w, ym4, d4); d5 = fmaf(w, ym5, d5);
            d6 = fmaf(w, ym6, d6); d7 = fmaf(w, ym7, d7); d8 = fmaf(w, ym8, d8);
            ym8=ym7; ym7=ym6; ym6=ym5; ym5=ym4; ym4=ym3; ym3=ym2; ym2=ym1; ym1=y0;
        }

        const int kmax = (S - s_first < 9) ? (S - s_first) : 9;
        float ss = ssA;
        #define SSUP(kk) { \
            const int jh = s_first + kk; \
            const int jl = jh - 64; \
            if (jh <= L - 1) { const float w = wrow[jh * WPITCH]; ss = fmaf(w,  w, ss); } \
            if (jl >= 0)     { const float w = wrow[jl * WPITCH]; ss = fmaf(-w, w, ss); } }
        #define EVALK(kk, dk) { \
            double pn, pd; \
            if (ss > 0.0f) { const double dd = (double)dk; pn = dd * fabs(dd); pd = (double)ss; } \
            else           { pn = 0.0; pd = 1.0; } \
            if (pn * bD > bN * pd) { bN = pn; bD = pd; bi = s_first + kk; } }
        EVALK(0, d0)
        if (1 < kmax) { SSUP(1) EVALK(1, d1) }
        if (2 < kmax) { SSUP(2) EVALK(2, d2) }
        if (3 < kmax) { SSUP(3) EVALK(3, d3) }
        if (4 < kmax) { SSUP(4) EVALK(4, d4) }
        if (5 < kmax) { SSUP(5) EVALK(5, d5) }
        if (6 < kmax) { SSUP(6) EVALK(6, d6) }
        if (7 < kmax) { SSUP(7) EVALK(7, d7) }
        if (8 < kmax) { SSUP(8) EVALK(8, d8) }
        #undef SSUP
        #undef EVALK
    }

    rsimN[sg * 64 + hh] = bN;
    rsimD[sg * 64 + hh] = bD;
    ridxB[sg * 64 + hh] = bi;
    __syncthreads();
    if (tid < 64) {
        // waves interleave s-order -> tie-break on smaller shift index
        // (exact ties have bitwise-equal (pn,pd) pairs).
        double mN = -1.0, mD = 0.0; int mi = 0x7fffffff;
        for (int g = 0; g < NWAVE; ++g) {
            const double vN = rsimN[g * 64 + tid];
            const double vD = rsimD[g * 64 + tid];
            const int    vi = ridxB[g * 64 + tid];
            const double a = vN * mD, b = mN * vD;
            if (a > b || (a == b && vi < mi)) { mN = vN; mD = vD; mi = vi; }
        }
        const int o = (t5 * 256 + bt) * 64 + tid;
        outN[o] = mN;
        outD[o] = mD;
        outS[o] = mi;
    }
}

// Kernel 2: merge 5 thetas + epilogue. 256 blocks (bt) x 256 threads.
__global__ __launch_bounds__(256) void merge_epilogue(
    const float* __restrict__ x, const float* __restrict__ y,
    const int* __restrict__ mask,
    const float* __restrict__ W1, const float* __restrict__ b1,
    const float* __restrict__ W2, const float* __restrict__ b2,
    const double* __restrict__ N, const double* __restrict__ D,
    const int* __restrict__ S,
    float* __restrict__ xf, double* __restrict__ psum, double* __restrict__ pcnt)
{
    __shared__ float  sx[64], sy[64], sh[64];
    __shared__ int    bS[64], bT[64];
    __shared__ double part[4][64], ssum[64], su[64];

    const int tid = threadIdx.x;
    const int bt  = blockIdx.x;
    const int g   = tid >> 6, i = tid & 63;

    if (tid < 64) {
        sx[tid] = x[bt * 64 + tid];
        sy[tid] = y[bt * 64 + tid];
    }
    __syncthreads();
    if (tid < 64) {
        // fc1 serial fmaf chain: bitwise-identical to kernel 1's sh
        float acc = 0.0f;
        const float* w1r = W1 + tid * 64;
        for (int k = 0; k < 64; ++k) acc = fmaf(sx[k], w1r[k], acc);
        acc += b1[tid];
        sh[tid] = acc * (float)mask[bt * 64 + tid];
        // merge across thetas: ascending t5, strictly greater replaces
        // (earlier theta keeps exact ties, matching the reference rule)
        double mN = -1.0, mD = 0.0; int mS = 0, mT = 0;
        for (int t5 = 0; t5 < 5; ++t5) {
            const int o = (t5 * 256 + bt) * 64 + tid;
            const double vN = N[o], vD = D[o];
            if (vN * mD > mN * vD) { mN = vN; mD = vD; mS = S[o]; mT = t5; }
        }
        bS[tid] = mS; bT[tid] = mT;
    }
    __syncthreads();

    // ssum[i] = sum over h of chosen window value at element i (4 grp x 16 h)
    {
        double acc = 0.0;
        for (int q = 0; q < 16; ++q) {
            const int h = g * 16 + q;
            const int t = bT[h];
            const double th2 = (t == 4) ? 1.2 : (0.8 + (double)t * ((1.2 - 0.8) / 4.0));
            const int Lh = (int)floor(64.0 * th2);
            const double rc = 64.0 / (double)Lh;
            const int jj = bS[h] - 63 + i;
            if (jj >= 0 && jj < Lh) {
                int sj = (int)floor((double)jj * rc);
                if (sj > 63) sj = 63;
                acc += (double)fmaf(sh[h], W2[sj * 64 + h], b2[sj]);
            }
        }
        part[g][i] = acc;
    }
    __syncthreads();
    if (tid < 64) {
        ssum[tid] = part[0][tid] + part[1][tid] + part[2][tid] + part[3][tid];
    }
    __syncthreads();
    // u = W1 * ssum + 64*b1 (4-way partial over inner dim)
    {
        double acc = 0.0;
        const int base = g * 16;
        for (int q = 0; q < 16; ++q)
            acc += (double)W1[i * 64 + base + q] * ssum[base + q];
        part[g][i] = acc;
    }
    __syncthreads();
    if (tid < 64) {
        su[tid] = 64.0 * (double)b1[tid]
                + part[0][tid] + part[1][tid] + part[2][tid] + part[3][tid];
    }
    __syncthreads();
    // out = W2 * u + 64*b2 (4-way partial over inner dim)
    {
        double acc = 0.0;
        const int base = g * 16;
        for (int q = 0; q < 16; ++q)
            acc += (double)W2[i * 64 + base + q] * su[base + q];
        part[g][i] = acc;
    }
    __syncthreads();
    if (tid < 64) {
        const double v = 64.0 * (double)b2[tid]
                       + part[0][tid] + part[1][tid] + part[2][tid] + part[3][tid];
        const float outf = (float)v;
        xf[bt * 64 + tid] = outf;
        const float yv = sy[tid];
        double pl = 0.0, pc = 0.0;
        if (yv != 0.0f) {
            const float d = outf - yv;
            pl = (double)(d * d);
            pc = 1.0;
        }
        for (int o = 32; o > 0; o >>= 1) {
            pl += __shfl_down(pl, o, 64);
            pc += __shfl_down(pc, o, 64);
        }
        if (tid == 0) { psum[bt] = pl; pcnt[bt] = pc; }
    }
}

__global__ __launch_bounds__(256) void finalize_loss(
    const double* __restrict__ psum, const double* __restrict__ pcnt,
    float* __restrict__ out)
{
    __shared__ double a[256], c[256];
    const int t = threadIdx.x;
    a[t] = psum[t];
    c[t] = pcnt[t];
    __syncthreads();
    for (int s = 128; s > 0; s >>= 1) {
        if (t < s) { a[t] += a[t + s]; c[t] += c[t + s]; }
        __syncthreads();
    }
    if (t == 0) out[0] = (float)(a[0] / c[0]);
}

extern "C" void kernel_launch(void* const* d_in, const int* in_sizes, int n_in,
                              void* d_out, int out_size, void* d_ws, size_t ws_size,
                              hipStream_t stream) {
    const float* x    = (const float*)d_in[0];
    const float* y    = (const float*)d_in[1];
    const int*   mask = (const int*)d_in[2];
    const float* W1   = (const float*)d_in[3];
    const float* b1   = (const float*)d_in[4];
    const float* W2   = (const float*)d_in[5];
    const float* b2   = (const float*)d_in[6];
    float* out = (float*)d_out;

    char* ws = (char*)d_ws;
    double* Nw   = (double*)(ws);             // 5*256*64 f64 = 640 KiB
    double* Dw   = (double*)(ws + 655360);    // 640 KiB
    int*    Sw   = (int*)(ws + 1310720);      // 320 KiB
    double* psum = (double*)(ws + 1638400);
    double* pcnt = (double*)(ws + 1640448);

    argaug_scan<<<1280, NT, 0, stream>>>(x, y, mask, W1, b1, W2, b2,
                                         Nw, Dw, Sw);
    merge_epilogue<<<256, 256, 0, stream>>>(x, y, mask, W1, b1, W2, b2,
                                            Nw, Dw, Sw,
                                            out + 1, psum, pcnt);
    finalize_loss<<<1, 256, 0, stream>>>(psum, pcnt, out);
}

// Round 16
// 42.963 us; speedup vs baseline: 1.0036x; 1.0036x over previous
//
#include <hip/hip_runtime.h>
#include <math.h>

#define NT 512
#define NWAVE 8
#define WPITCH 65           // padded pitch (f32) -- conflict-free strided reads

// Kernel 1: grid 1280 = (theta t5 = bx>>8) x (bt = bx&255), 512 threads.
// 8 waves; lane = channel hh; wave w owns strips {w, w+8} (9 shifts each):
// span(w)+span(w+8) == L exactly -> perfect balance. Window table f32 in LDS
// (pitch 65). Dots/ss in f32 (same bits/order as round-14's passing kernel);
// candidate comparison via exact f64 cross-multiplication of f32-origin
// values (24-bit mantissas -> exact products) -> deterministic ordering,
// first-index ties. LDS ~31 KB, VGPR <= 64 -> 4 blocks/CU (32 waves).
__global__ __launch_bounds__(NT) void argaug_scan(
    const float* __restrict__ x, const float* __restrict__ y,
    const int* __restrict__ mask,
    const float* __restrict__ W1, const float* __restrict__ b1,
    const float* __restrict__ W2, const float* __restrict__ b2,
    double* __restrict__ outN, double* __restrict__ outD, int* __restrict__ outS)
{
    __shared__ float  wdBuf[76 * WPITCH];      // 19760 B
    __shared__ float  ypad[80];                // ypad[p] = y[p-8], p in [8,71], else 0
    __shared__ float  sx[64], sh[64], sb1[64];
    __shared__ double rsimN[NWAVE * 64], rsimD[NWAVE * 64];
    __shared__ int    ridxB[NWAVE * 64];

    const int tid = threadIdx.x;
    const int bx  = blockIdx.x;
    const int bt  = bx & 255;
    const int t5  = bx >> 8;
    const int hh  = tid & 63;
    const int sg  = tid >> 6;

    const double theta = (t5 == 4) ? 1.2 : (0.8 + (double)t5 * ((1.2 - 0.8) / 4.0));
    const int L = (int)floor(64.0 * theta);   // {51,57,64,70,76}
    const int S = L + 63;
    const double rcp = 64.0 / (double)L;

    if (tid < 64) {
        sx[tid]  = x[bt * 64 + tid];
        sb1[tid] = b1[tid];
    } else if (tid >= 128 && tid < 208) {
        const int p = tid - 128;
        ypad[p] = (p >= 8 && p < 72) ? y[bt * 64 + p - 8] : 0.0f;
    }
    __syncthreads();

    if (tid < 64) {
        // fc1: serial fmaf chain, bitwise-identical across all rounds
        float acc = 0.0f;
        const float* w1r = W1 + tid * 64;
        for (int i = 0; i < 64; ++i) acc = fmaf(sx[i], w1r[i], acc);
        acc += sb1[tid];
        sh[tid] = acc * (float)mask[bt * 64 + tid];
    }
    __syncthreads();

    // Phase A: wd[j][h] = sh[h]*W2[src(j)][h] + b2[src(j)]  (f32)
    for (int k = tid; k < L * 64; k += NT) {
        const int j = k >> 6, h = k & 63;     // j wave-uniform
        int sj = (int)floor((double)j * rcp);
        if (sj > 63) sj = 63;
        wdBuf[j * WPITCH + h] = fmaf(sh[h], W2[sj * 64 + h], b2[sj]);
    }
    __syncthreads();

    const float* wrow = wdBuf + hh;           // row j at wrow[j*WPITCH]

    double bN = -1.0, bD = 0.0; int bi = 0x7fffffff;
    #pragma unroll 2
    for (int pp = 0; pp < 2; ++pp) {
        const int s_first = 9 * (sg + 8 * pp);
        if (s_first >= S) continue;
        const int jstart = (s_first > 63) ? (s_first - 63) : 0;
        const int jmid   = (s_first < L - 1) ? s_first : (L - 1);
        const int jend   = (s_first + 8 < L - 1) ? (s_first + 8) : (L - 1);
        const int C      = 71 - s_first;      // ypad idx = j + C - k

        float d0=0,d1=0,d2=0,d3=0,d4=0,d5=0,d6=0,d7=0,d8=0,ssA=0;
        float ym1 = ypad[jstart + C - 1];
        float ym2 = ypad[jstart + C - 2];
        float ym3 = ypad[jstart + C - 3];
        float ym4 = ypad[jstart + C - 4];
        float ym5 = ypad[jstart + C - 5];
        float ym6 = ypad[jstart + C - 6];
        float ym7 = ypad[jstart + C - 7];
        float ym8 = ypad[jstart + C - 8];

        #pragma unroll 9
        for (int j = jstart; j <= jmid; ++j) {
            const float w  = wrow[j * WPITCH];
            const float y0 = ypad[j + C];
            d0 = fmaf(w, y0,  d0); d1 = fmaf(w, ym1, d1); d2 = fmaf(w, ym2, d2);
            d3 = fmaf(w, ym3, d3); d4 = fmaf(w, ym4, d4); d5 = fmaf(w, ym5, d5);
            d6 = fmaf(w, ym6, d6); d7 = fmaf(w, ym7, d7); d8 = fmaf(w, ym8, d8);
            ssA = fmaf(w, w, ssA);
            ym8=ym7; ym7=ym6; ym6=ym5; ym5=ym4; ym4=ym3; ym3=ym2; ym2=ym1; ym1=y0;
        }
        #pragma unroll 9
        for (int j = jmid + 1; j <= jend; ++j) {
            const float w  = wrow[j * WPITCH];
            const float y0 = ypad[j + C];
            d0 = fmaf(w, y0,  d0); d1 = fmaf(w, ym1, d1); d2 = fmaf(w, ym2, d2);
            d3 = fmaf(w, ym3, d3); d4 = fmaf(w, ym4, d4); d5 = fmaf(w, ym5, d5);
            d6 = fmaf(w, ym6, d6); d7 = fmaf(w, ym7, d7); d8 = fmaf(w, ym8, d8);
            ym8=ym7; ym7=ym6; ym6=ym5; ym5=ym4; ym4=ym3; ym3=ym2; ym2=ym1; ym1=y0;
        }

        const int kmax = (S - s_first < 9) ? (S - s_first) : 9;
        float ss = ssA;
        #define SSUP(kk) { \
            const int jh = s_first + kk; \
            const int jl = jh - 64; \
            if (jh <= L - 1) { const float w = wrow[jh * WPITCH]; ss = fmaf(w,  w, ss); } \
            if (jl >= 0)     { const float w = wrow[jl * WPITCH]; ss = fmaf(-w, w, ss); } }
        #define EVALK(kk, dk) { \
            double pn, pd; \
            if (ss > 0.0f) { const double dd = (double)dk; pn = dd * fabs(dd); pd = (double)ss; } \
            else           { pn = 0.0; pd = 1.0; } \
            if (pn * bD > bN * pd) { bN = pn; bD = pd; bi = s_first + kk; } }
        EVALK(0, d0)
        if (1 < kmax) { SSUP(1) EVALK(1, d1) }
        if (2 < kmax) { SSUP(2) EVALK(2, d2) }
        if (3 < kmax) { SSUP(3) EVALK(3, d3) }
        if (4 < kmax) { SSUP(4) EVALK(4, d4) }
        if (5 < kmax) { SSUP(5) EVALK(5, d5) }
        if (6 < kmax) { SSUP(6) EVALK(6, d6) }
        if (7 < kmax) { SSUP(7) EVALK(7, d7) }
        if (8 < kmax) { SSUP(8) EVALK(8, d8) }
        #undef SSUP
        #undef EVALK
    }

    rsimN[sg * 64 + hh] = bN;
    rsimD[sg * 64 + hh] = bD;
    ridxB[sg * 64 + hh] = bi;
    __syncthreads();
    if (tid < 64) {
        // waves interleave s-order -> tie-break on smaller shift index
        // (exact ties have bitwise-equal (pn,pd) pairs).
        double mN = -1.0, mD = 0.0; int mi = 0x7fffffff;
        for (int g = 0; g < NWAVE; ++g) {
            const double vN = rsimN[g * 64 + tid];
            const double vD = rsimD[g * 64 + tid];
            const int    vi = ridxB[g * 64 + tid];
            const double a = vN * mD, b = mN * vD;
            if (a > b || (a == b && vi < mi)) { mN = vN; mD = vD; mi = vi; }
        }
        const int o = (t5 * 256 + bt) * 64 + tid;
        outN[o] = mN;
        outD[o] = mD;
        outS[o] = mi;
    }
}

// Kernel 2: merge 5 thetas + epilogue. 256 blocks (bt) x 256 threads.
__global__ __launch_bounds__(256) void merge_epilogue(
    const float* __restrict__ x, const float* __restrict__ y,
    const int* __restrict__ mask,
    const float* __restrict__ W1, const float* __restrict__ b1,
    const float* __restrict__ W2, const float* __restrict__ b2,
    const double* __restrict__ N, const double* __restrict__ D,
    const int* __restrict__ S,
    float* __restrict__ xf, double* __restrict__ psum, double* __restrict__ pcnt)
{
    __shared__ float  sx[64], sy[64], sh[64];
    __shared__ int    bS[64], bT[64];
    __shared__ double part[4][64], ssum[64], su[64];

    const int tid = threadIdx.x;
    const int bt  = blockIdx.x;
    const int g   = tid >> 6, i = tid & 63;

    if (tid < 64) {
        sx[tid] = x[bt * 64 + tid];
        sy[tid] = y[bt * 64 + tid];
    }
    __syncthreads();
    if (tid < 64) {
        // fc1 serial fmaf chain: bitwise-identical to kernel 1's sh
        float acc = 0.0f;
        const float* w1r = W1 + tid * 64;
        for (int k = 0; k < 64; ++k) acc = fmaf(sx[k], w1r[k], acc);
        acc += b1[tid];
        sh[tid] = acc * (float)mask[bt * 64 + tid];
        // merge across thetas: ascending t5, strictly greater replaces
        // (earlier theta keeps exact ties, matching the reference rule)
        double mN = -1.0, mD = 0.0; int mS = 0, mT = 0;
        for (int t5 = 0; t5 < 5; ++t5) {
            const int o = (t5 * 256 + bt) * 64 + tid;
            const double vN = N[o], vD = D[o];
            if (vN * mD > mN * vD) { mN = vN; mD = vD; mS = S[o]; mT = t5; }
        }
        bS[tid] = mS; bT[tid] = mT;
    }
    __syncthreads();

    // ssum[i] = sum over h of chosen window value at element i (4 grp x 16 h)
    {
        double acc = 0.0;
        for (int q = 0; q < 16; ++q) {
            const int h = g * 16 + q;
            const int t = bT[h];
            const double th2 = (t == 4) ? 1.2 : (0.8 + (double)t * ((1.2 - 0.8) / 4.0));
            const int Lh = (int)floor(64.0 * th2);
            const double rc = 64.0 / (double)Lh;
            const int jj = bS[h] - 63 + i;
            if (jj >= 0 && jj < Lh) {
                int sj = (int)floor((double)jj * rc);
                if (sj > 63) sj = 63;
                acc += (double)fmaf(sh[h], W2[sj * 64 + h], b2[sj]);
            }
        }
        part[g][i] = acc;
    }
    __syncthreads();
    if (tid < 64) {
        ssum[tid] = part[0][tid] + part[1][tid] + part[2][tid] + part[3][tid];
    }
    __syncthreads();
    // u = W1 * ssum + 64*b1 (4-way partial over inner dim)
    {
        double acc = 0.0;
        const int base = g * 16;
        for (int q = 0; q < 16; ++q)
            acc += (double)W1[i * 64 + base + q] * ssum[base + q];
        part[g][i] = acc;
    }
    __syncthreads();
    if (tid < 64) {
        su[tid] = 64.0 * (double)b1[tid]
                + part[0][tid] + part[1][tid] + part[2][tid] + part[3][tid];
    }
    __syncthreads();
    // out = W2 * u + 64*b2 (4-way partial over inner dim)
    {
        double acc = 0.0;
        const int base = g * 16;
        for (int q = 0; q < 16; ++q)
            acc += (double)W2[i * 64 + base + q] * su[base + q];
        part[g][i] = acc;
    }
    __syncthreads();
    if (tid < 64) {
        const double v = 64.0 * (double)b2[tid]
                       + part[0][tid] + part[1][tid] + part[2][tid] + part[3][tid];
        const float outf = (float)v;
        xf[bt * 64 + tid] = outf;
        const float yv = sy[tid];
        double pl = 0.0, pc = 0.0;
        if (yv != 0.0f) {
            const float d = outf - yv;
            pl = (double)(d * d);
            pc = 1.0;
        }
        for (int o = 32; o > 0; o >>= 1) {
            pl += __shfl_down(pl, o, 64);
            pc += __shfl_down(pc, o, 64);
        }
        if (tid == 0) { psum[bt] = pl; pcnt[bt] = pc; }
    }
}

__global__ __launch_bounds__(256) void finalize_loss(
    const double* __restrict__ psum, const double* __restrict__ pcnt,
    float* __restrict__ out)
{
    __shared__ double a[256], c[256];
    const int t = threadIdx.x;
    a[t] = psum[t];
    c[t] = pcnt[t];
    __syncthreads();
    for (int s = 128; s > 0; s >>= 1) {
        if (t < s) { a[t] += a[t + s]; c[t] += c[t + s]; }
        __syncthreads();
    }
    if (t == 0) out[0] = (float)(a[0] / c[0]);
}

extern "C" void kernel_launch(void* const* d_in, const int* in_sizes, int n_in,
                              void* d_out, int out_size, void* d_ws, size_t ws_size,
                              hipStream_t stream) {
    const float* x    = (const float*)d_in[0];
    const float* y    = (const float*)d_in[1];
    const int*   mask = (const int*)d_in[2];
    const float* W1   = (const float*)d_in[3];
    const float* b1   = (const float*)d_in[4];
    const float* W2   = (const float*)d_in[5];
    const float* b2   = (const float*)d_in[6];
    float* out = (float*)d_out;

    char* ws = (char*)d_ws;
    double* Nw   = (double*)(ws);             // 5*256*64 f64 = 640 KiB
    double* Dw   = (double*)(ws + 655360);    // 640 KiB
    int*    Sw   = (int*)(ws + 1310720);      // 320 KiB
    double* psum = (double*)(ws + 1638400);
    double* pcnt = (double*)(ws + 1640448);

    argaug_scan<<<1280, NT, 0, stream>>>(x, y, mask, W1, b1, W2, b2,
                                         Nw, Dw, Sw);
    merge_epilogue<<<256, 256, 0, stream>>>(x, y, mask, W1, b1, W2, b2,
                                            Nw, Dw, Sw,
                                            out + 1, psum, pcnt);
    finalize_loss<<<1, 256, 0, stream>>>(psum, pcnt, out);
}

// Round 17
// 42.914 us; speedup vs baseline: 1.0048x; 1.0011x over previous
//
#include <hip/hip_runtime.h>
#include <math.h>

#define NT 512
#define NWAVE 8
#define WPITCH 65           // padded pitch (f32) -- conflict-free strided reads

// Kernel 1: grid 1280 = (theta t5 = bx>>8) x (bt = bx&255), 512 threads.
// 8 waves; lane = channel hh; wave w owns strips {w, w+8} (9 shifts each):
// span(w)+span(w+8) == L exactly -> perfect balance. Window table f32 in LDS
// (pitch 65). Dots/ss in f32 (same bits/order as round-14's passing kernel);
// candidate comparison via exact f64 cross-multiplication of f32-origin
// values (24-bit mantissas -> exact products) -> deterministic ordering,
// first-index ties. LDS ~31 KB, VGPR <= 64 -> 4 blocks/CU (32 waves).
__global__ __launch_bounds__(NT) void argaug_scan(
    const float* __restrict__ x, const float* __restrict__ y,
    const int* __restrict__ mask,
    const float* __restrict__ W1, const float* __restrict__ b1,
    const float* __restrict__ W2, const float* __restrict__ b2,
    double* __restrict__ outN, double* __restrict__ outD, int* __restrict__ outS)
{
    __shared__ float  wdBuf[76 * WPITCH];      // 19760 B
    __shared__ float  ypad[80];                // ypad[p] = y[p-8], p in [8,71], else 0
    __shared__ float  sx[64], sh[64], sb1[64];
    __shared__ double rsimN[NWAVE * 64], rsimD[NWAVE * 64];
    __shared__ int    ridxB[NWAVE * 64];

    const int tid = threadIdx.x;
    const int bx  = blockIdx.x;
    const int bt  = bx & 255;
    const int t5  = bx >> 8;
    const int hh  = tid & 63;
    const int sg  = tid >> 6;

    const double theta = (t5 == 4) ? 1.2 : (0.8 + (double)t5 * ((1.2 - 0.8) / 4.0));
    const int L = (int)floor(64.0 * theta);   // {51,57,64,70,76}
    const int S = L + 63;
    const double rcp = 64.0 / (double)L;

    if (tid < 64) {
        sx[tid]  = x[bt * 64 + tid];
        sb1[tid] = b1[tid];
    } else if (tid >= 128 && tid < 208) {
        const int p = tid - 128;
        ypad[p] = (p >= 8 && p < 72) ? y[bt * 64 + p - 8] : 0.0f;
    }
    __syncthreads();

    if (tid < 64) {
        // fc1: serial fmaf chain, bitwise-identical across all rounds
        float acc = 0.0f;
        const float* w1r = W1 + tid * 64;
        for (int i = 0; i < 64; ++i) acc = fmaf(sx[i], w1r[i], acc);
        acc += sb1[tid];
        sh[tid] = acc * (float)mask[bt * 64 + tid];
    }
    __syncthreads();

    // Phase A: wd[j][h] = sh[h]*W2[src(j)][h] + b2[src(j)]  (f32)
    for (int k = tid; k < L * 64; k += NT) {
        const int j = k >> 6, h = k & 63;     // j wave-uniform
        int sj = (int)floor((double)j * rcp);
        if (sj > 63) sj = 63;
        wdBuf[j * WPITCH + h] = fmaf(sh[h], W2[sj * 64 + h], b2[sj]);
    }
    __syncthreads();

    const float* wrow = wdBuf + hh;           // row j at wrow[j*WPITCH]

    double bN = -1.0, bD = 0.0; int bi = 0x7fffffff;
    #pragma unroll 2
    for (int pp = 0; pp < 2; ++pp) {
        const int s_first = 9 * (sg + 8 * pp);
        if (s_first >= S) continue;
        const int jstart = (s_first > 63) ? (s_first - 63) : 0;
        const int jmid   = (s_first < L - 1) ? s_first : (L - 1);
        const int jend   = (s_first + 8 < L - 1) ? (s_first + 8) : (L - 1);
        const int C      = 71 - s_first;      // ypad idx = j + C - k

        float d0=0,d1=0,d2=0,d3=0,d4=0,d5=0,d6=0,d7=0,d8=0,ssA=0;
        float ym1 = ypad[jstart + C - 1];
        float ym2 = ypad[jstart + C - 2];
        float ym3 = ypad[jstart + C - 3];
        float ym4 = ypad[jstart + C - 4];
        float ym5 = ypad[jstart + C - 5];
        float ym6 = ypad[jstart + C - 6];
        float ym7 = ypad[jstart + C - 7];
        float ym8 = ypad[jstart + C - 8];

        #pragma unroll 9
        for (int j = jstart; j <= jmid; ++j) {
            const float w  = wrow[j * WPITCH];
            const float y0 = ypad[j + C];
            d0 = fmaf(w, y0,  d0); d1 = fmaf(w, ym1, d1); d2 = fmaf(w, ym2, d2);
            d3 = fmaf(w, ym3, d3); d4 = fmaf(w, ym4, d4); d5 = fmaf(w, ym5, d5);
            d6 = fmaf(w, ym6, d6); d7 = fmaf(w, ym7, d7); d8 = fmaf(w, ym8, d8);
            ssA = fmaf(w, w, ssA);
            ym8=ym7; ym7=ym6; ym6=ym5; ym5=ym4; ym4=ym3; ym3=ym2; ym2=ym1; ym1=y0;
        }
        #pragma unroll 9
        for (int j = jmid + 1; j <= jend; ++j) {
            const float w  = wrow[j * WPITCH];
            const float y0 = ypad[j + C];
            d0 = fmaf(w, y0,  d0); d1 = fmaf(w, ym1, d1); d2 = fmaf(w, ym2, d2);
            d3 = fmaf(w, ym3, d3); d4 = fmaf(w, ym4, d4); d5 = fmaf(w, ym5, d5);
            d6 = fmaf(w, ym6, d6); d7 = fmaf(w, ym7, d7); d8 = fmaf(w, ym8, d8);
            ym8=ym7; ym7=ym6; ym6=ym5; ym5=ym4; ym4=ym3; ym3=ym2; ym2=ym1; ym1=y0;
        }

        const int kmax = (S - s_first < 9) ? (S - s_first) : 9;
        float ss = ssA;
        #define SSUP(kk) { \
            const int jh = s_first + kk; \
            const int jl = jh - 64; \
            if (jh <= L - 1) { const float w = wrow[jh * WPITCH]; ss = fmaf(w,  w, ss); } \
            if (jl >= 0)     { const float w = wrow[jl * WPITCH]; ss = fmaf(-w, w, ss); } }
        #define EVALK(kk, dk) { \
            double pn, pd; \
            if (ss > 0.0f) { const double dd = (double)dk; pn = dd * fabs(dd); pd = (double)ss; } \
            else           { pn = 0.0; pd = 1.0; } \
            if (pn * bD > bN * pd) { bN = pn; bD = pd; bi = s_first + kk; } }
        EVALK(0, d0)
        if (1 < kmax) { SSUP(1) EVALK(1, d1) }
        if (2 < kmax) { SSUP(2) EVALK(2, d2) }
        if (3 < kmax) { SSUP(3) EVALK(3, d3) }
        if (4 < kmax) { SSUP(4) EVALK(4, d4) }
        if (5 < kmax) { SSUP(5) EVALK(5, d5) }
        if (6 < kmax) { SSUP(6) EVALK(6, d6) }
        if (7 < kmax) { SSUP(7) EVALK(7, d7) }
        if (8 < kmax) { SSUP(8) EVALK(8, d8) }
        #undef SSUP
        #undef EVALK
    }

    rsimN[sg * 64 + hh] = bN;
    rsimD[sg * 64 + hh] = bD;
    ridxB[sg * 64 + hh] = bi;
    __syncthreads();
    if (tid < 64) {
        // waves interleave s-order -> tie-break on smaller shift index
        // (exact ties have bitwise-equal (pn,pd) pairs).
        double mN = -1.0, mD = 0.0; int mi = 0x7fffffff;
        for (int g = 0; g < NWAVE; ++g) {
            const double vN = rsimN[g * 64 + tid];
            const double vD = rsimD[g * 64 + tid];
            const int    vi = ridxB[g * 64 + tid];
            const double a = vN * mD, b = mN * vD;
            if (a > b || (a == b && vi < mi)) { mN = vN; mD = vD; mi = vi; }
        }
        const int o = (t5 * 256 + bt) * 64 + tid;
        outN[o] = mN;
        outD[o] = mD;
        outS[o] = mi;
    }
}

// Kernel 2: merge 5 thetas + epilogue. 256 blocks (bt) x 256 threads.
__global__ __launch_bounds__(256) void merge_epilogue(
    const float* __restrict__ x, const float* __restrict__ y,
    const int* __restrict__ mask,
    const float* __restrict__ W1, const float* __restrict__ b1,
    const float* __restrict__ W2, const float* __restrict__ b2,
    const double* __restrict__ N, const double* __restrict__ D,
    const int* __restrict__ S,
    float* __restrict__ xf, double* __restrict__ psum, double* __restrict__ pcnt)
{
    __shared__ float  sx[64], sy[64], sh[64];
    __shared__ int    bS[64], bT[64];
    __shared__ double part[4][64], ssum[64], su[64];

    const int tid = threadIdx.x;
    const int bt  = blockIdx.x;
    const int g   = tid >> 6, i = tid & 63;

    if (tid < 64) {
        sx[tid] = x[bt * 64 + tid];
        sy[tid] = y[bt * 64 + tid];
    }
    __syncthreads();
    if (tid < 64) {
        // fc1 serial fmaf chain: bitwise-identical to kernel 1's sh
        float acc = 0.0f;
        const float* w1r = W1 + tid * 64;
        for (int k = 0; k < 64; ++k) acc = fmaf(sx[k], w1r[k], acc);
        acc += b1[tid];
        sh[tid] = acc * (float)mask[bt * 64 + tid];
        // merge across thetas: ascending t5, strictly greater replaces
        // (earlier theta keeps exact ties, matching the reference rule)
        double mN = -1.0, mD = 0.0; int mS = 0, mT = 0;
        for (int t5 = 0; t5 < 5; ++t5) {
            const int o = (t5 * 256 + bt) * 64 + tid;
            const double vN = N[o], vD = D[o];
            if (vN * mD > mN * vD) { mN = vN; mD = vD; mS = S[o]; mT = t5; }
        }
        bS[tid] = mS; bT[tid] = mT;
    }
    __syncthreads();

    // ssum[i] = sum over h of chosen window value at element i (4 grp x 16 h)
    {
        double acc = 0.0;
        for (int q = 0; q < 16; ++q) {
            const int h = g * 16 + q;
            const int t = bT[h];
            const double th2 = (t == 4) ? 1.2 : (0.8 + (double)t * ((1.2 - 0.8) / 4.0));
            const int Lh = (int)floor(64.0 * th2);
            const double rc = 64.0 / (double)Lh;
            const int jj = bS[h] - 63 + i;
            if (jj >= 0 && jj < Lh) {
                int sj = (int)floor((double)jj * rc);
                if (sj > 63) sj = 63;
                acc += (double)fmaf(sh[h], W2[sj * 64 + h], b2[sj]);
            }
        }
        part[g][i] = acc;
    }
    __syncthreads();
    if (tid < 64) {
        ssum[tid] = part[0][tid] + part[1][tid] + part[2][tid] + part[3][tid];
    }
    __syncthreads();
    // u = W1 * ssum + 64*b1 (4-way partial over inner dim)
    {
        double acc = 0.0;
        const int base = g * 16;
        for (int q = 0; q < 16; ++q)
            acc += (double)W1[i * 64 + base + q] * ssum[base + q];
        part[g][i] = acc;
    }
    __syncthreads();
    if (tid < 64) {
        su[tid] = 64.0 * (double)b1[tid]
                + part[0][tid] + part[1][tid] + part[2][tid] + part[3][tid];
    }
    __syncthreads();
    // out = W2 * u + 64*b2 (4-way partial over inner dim)
    {
        double acc = 0.0;
        const int base = g * 16;
        for (int q = 0; q < 16; ++q)
            acc += (double)W2[i * 64 + base + q] * su[base + q];
        part[g][i] = acc;
    }
    __syncthreads();
    if (tid < 64) {
        const double v = 64.0 * (double)b2[tid]
                       + part[0][tid] + part[1][tid] + part[2][tid] + part[3][tid];
        const float outf = (float)v;
        xf[bt * 64 + tid] = outf;
        const float yv = sy[tid];
        double pl = 0.0, pc = 0.0;
        if (yv != 0.0f) {
            const float d = outf - yv;
            pl = (double)(d * d);
            pc = 1.0;
        }
        for (int o = 32; o > 0; o >>= 1) {
            pl += __shfl_down(pl, o, 64);
            pc += __shfl_down(pc, o, 64);
        }
        if (tid == 0) { psum[bt] = pl; pcnt[bt] = pc; }
    }
}

__global__ __launch_bounds__(256) void finalize_loss(
    const double* __restrict__ psum, const double* __restrict__ pcnt,
    float* __restrict__ out)
{
    __shared__ double a[256], c[256];
    const int t = threadIdx.x;
    a[t] = psum[t];
    c[t] = pcnt[t];
    __syncthreads();
    for (int s = 128; s > 0; s >>= 1) {
        if (t < s) { a[t] += a[t + s]; c[t] += c[t + s]; }
        __syncthreads();
    }
    if (t == 0) out[0] = (float)(a[0] / c[0]);
}

extern "C" void kernel_launch(void* const* d_in, const int* in_sizes, int n_in,
                              void* d_out, int out_size, void* d_ws, size_t ws_size,
                              hipStream_t stream) {
    const float* x    = (const float*)d_in[0];
    const float* y    = (const float*)d_in[1];
    const int*   mask = (const int*)d_in[2];
    const float* W1   = (const float*)d_in[3];
    const float* b1   = (const float*)d_in[4];
    const float* W2   = (const float*)d_in[5];
    const float* b2   = (const float*)d_in[6];
    float* out = (float*)d_out;

    char* ws = (char*)d_ws;
    double* Nw   = (double*)(ws);             // 5*256*64 f64 = 640 KiB
    double* Dw   = (double*)(ws + 655360);    // 640 KiB
    int*    Sw   = (int*)(ws + 1310720);      // 320 KiB
    double* psum = (double*)(ws + 1638400);
    double* pcnt = (double*)(ws + 1640448);

    argaug_scan<<<1280, NT, 0, stream>>>(x, y, mask, W1, b1, W2, b2,
                                         Nw, Dw, Sw);
    merge_epilogue<<<256, 256, 0, stream>>>(x, y, mask, W1, b1, W2, b2,
                                            Nw, Dw, Sw,
                                            out + 1, psum, pcnt);
    finalize_loss<<<1, 256, 0, stream>>>(psum, pcnt, out);
}